// Round 3
// baseline (1784.029 us; speedup 1.0000x reference)
//
#include <hip/hip_runtime.h>

// 2-layer stacked LSTM: B=256, T=2048, H=64, layer2 hidden=1.
//
// Round-6: single-variable fix on top of the Round-5 one-wave restructure.
// Round-5 post-mortem: VGPR_Count=180 vs ~360 live values/lane -> the
// allocator spilled ~half the W1 panel to scratch and re-loaded it every
// timestep (2030 cy/step). Root cause: amdgpu_waves_per_eu(1) sets only a
// MINIMUM occupancy -- it does not cap the backend's default occupancy
// target (LDS 16.9KB -> ~2-3 waves/EU -> ~180 VGPR budget). Fix:
// amdgpu_waves_per_eu(1, 1) hard-caps max waves/EU at 1, granting the full
// 512-VGPR budget (no spill through ~450 regs per HW measurement).
//
// Structure (unchanged from Round-5): ONE WAVE per batch element
// (256 blocks x 64 threads). Lane l owns layer-1 unit l, all 4 gates; the
// 65x256 W1 panel lives as 256 f32/lane in VGPRs as f32x2 pairs
// (v_pk_fma_f32). Zero __syncthreads: same-wave DS ops are in-order, so the
// h1 ds_write -> next-step ds_read needs no barrier. Layer 2 in the same
// wave, split head (DPP row-reduce) / tail (readlane combine + activations,
// deferred one step so it hides the LDS h1 read latency).
constexpr int kT = 2048;
constexpr int kB = 256;
constexpr int kH = 64;

typedef __attribute__((ext_vector_type(2))) float f32x2;
typedef __attribute__((ext_vector_type(4))) float f32x4;

__device__ __forceinline__ float fast_sig(float x) {
    return __builtin_amdgcn_rcpf(1.0f + __expf(-x));
}
__device__ __forceinline__ float fast_tanh(float x) {
    float t = __expf(2.0f * x);
    return 1.0f - 2.0f * __builtin_amdgcn_rcpf(t + 1.0f);
}
__device__ __forceinline__ float rl(float v, int lane) {
    return __int_as_float(__builtin_amdgcn_readlane(__float_as_int(v), lane));
}
// One butterfly level as a DPP add (VALU pipe, no LDS).
template <int CTRL>
__device__ __forceinline__ float dpp_add(float v) {
    int t = __builtin_amdgcn_update_dpp(0, __float_as_int(v), CTRL, 0xF, 0xF, true);
    return v + __int_as_float(t);
}
// All 16 lanes of each row end with the row sum.
__device__ __forceinline__ float row_reduce16(float v) {
    v = dpp_add<0xB1>(v);   // quad_perm [1,0,3,2]  (xor 1)
    v = dpp_add<0x4E>(v);   // quad_perm [2,3,0,1]  (xor 2)
    v = dpp_add<0x141>(v);  // row_half_mirror      (8-group sum)
    v = dpp_add<0x140>(v);  // row_mirror           (16-group sum)
    return v;
}

__global__ __launch_bounds__(64)
__attribute__((amdgpu_waves_per_eu(1, 1)))
void lstm2_kernel(
    const float* __restrict__ x, const float* __restrict__ W1,
    const float* __restrict__ b1, const float* __restrict__ W2,
    const float* __restrict__ b2, float* __restrict__ out)
{
    __shared__ f32x4 x4_lds[kT / 4];     // whole input row
    __shared__ f32x4 out4_lds[kT / 4];   // h2 staging, bulk-stored at the end
    __shared__ f32x4 h4_lds[kH / 4];     // h1(t-1), republished every step
    float* x_lds = (float*)x4_lds;
    float* out_lds = (float*)out4_lds;
    float* h_lds = (float*)h4_lds;

    const int l = threadIdx.x;           // lane == layer-1 unit id
    const int b = blockIdx.x;
    const f32x4* xg4 = (const f32x4*)(x + (size_t)b * kT);
    f32x4* outg4 = (f32x4*)(out + (size_t)b * kT);

    for (int i = l; i < kT / 4; i += 64) x4_lds[i] = xg4[i];
    h_lds[l] = 0.0f;

    // ---- per-lane weights: W1 columns for unit l, all 4 gates ----
    // wp[g][j] pairs with (h[2j], h[2j+1]); W1 row r+1 multiplies h[r].
    f32x2 wp[4][32];
    float w0g[4], bg[4], w2r[4];
    #pragma unroll
    for (int g = 0; g < 4; ++g) {
        const int col = g * 64 + l;      // gate-major: i, j, f, o quarters
        w0g[g] = W1[col];
        bg[g]  = b1[col];
        #pragma unroll
        for (int j = 0; j < 32; ++j) {
            wp[g][j].x = W1[(2 * j + 1) * 256 + col];
            wp[g][j].y = W1[(2 * j + 2) * 256 + col];
        }
        w2r[g] = W2[l * 4 + g];          // layer-2 weight for h1[l], gate g
    }
    f32x4 w2t = ((const f32x4*)W2)[kH];  // W2[64][0..3]: h2 recurrent row
    f32x4 b2v = ((const f32x4*)b2)[0];

    // ---- PIN loop invariants into registers (opaque RMW) ----
    #pragma unroll
    for (int g = 0; g < 4; ++g) {
        #pragma unroll
        for (int j = 0; j < 32; ++j) asm volatile("" : "+v"(wp[g][j]));
        asm volatile("" : "+v"(w0g[g]), "+v"(bg[g]), "+v"(w2r[g]));
    }
    asm volatile("" : "+v"(w2t), "+v"(b2v));

    float c1 = 0.0f, h1own = 0.0f, c2 = 0.0f, h2 = 0.0f;
    float r0 = 0.0f, r1 = 0.0f, r2 = 0.0f, r3 = 0.0f;  // staged row sums

    #pragma unroll 1
    for (int t = 0; t < kT; ++t) {
        // Issue this step's operand reads first. They sit behind last step's
        // h_lds write in the wave's in-order DS queue, so they observe
        // h1(t-1); their latency hides under the deferred layer-2 tail.
        const float xt = x_lds[t];
        f32x4 h4[16];
        #pragma unroll
        for (int k = 0; k < 16; ++k) h4[k] = h4_lds[k];

        // ---- layer-2 tail for step t-1: cross-row combine + activations ----
        if (t != 0) {
            const float zi = rl(r0,0)+rl(r0,16)+rl(r0,32)+rl(r0,48) + b2v.x + h2 * w2t.x;
            const float zj = rl(r1,0)+rl(r1,16)+rl(r1,32)+rl(r1,48) + b2v.y + h2 * w2t.y;
            const float zf = rl(r2,0)+rl(r2,16)+rl(r2,32)+rl(r2,48) + b2v.z + h2 * w2t.z;
            const float zo = rl(r3,0)+rl(r3,16)+rl(r3,32)+rl(r3,48) + b2v.w + h2 * w2t.w;
            c2 = fast_sig(zf + 1.0f) * c2 + fast_sig(zi) * fast_tanh(zj);
            h2 = fast_sig(zo) * fast_tanh(c2);
            if (l == 0) out_lds[t - 1] = h2;
        }

        // ---- layer-1: z[g] = b + x*w0 + sum_k h[k]*W[k], packed pairs ----
        f32x2 a0 = {fmaf(xt, w0g[0], bg[0]), 0.0f};
        f32x2 a1 = {fmaf(xt, w0g[1], bg[1]), 0.0f};
        f32x2 a2 = {fmaf(xt, w0g[2], bg[2]), 0.0f};
        f32x2 a3 = {fmaf(xt, w0g[3], bg[3]), 0.0f};
        #pragma unroll
        for (int k = 0; k < 16; ++k) {
            const f32x2 lo = h4[k].xy;
            const f32x2 hi = h4[k].zw;
            a0 += lo * wp[0][2*k]; a0 += hi * wp[0][2*k+1];
            a1 += lo * wp[1][2*k]; a1 += hi * wp[1][2*k+1];
            a2 += lo * wp[2][2*k]; a2 += hi * wp[2][2*k+1];
            a3 += lo * wp[3][2*k]; a3 += hi * wp[3][2*k+1];
        }
        const float gi = fast_sig (a0.x + a0.y);
        const float gj = fast_tanh(a1.x + a1.y);
        const float gf = fast_sig (a2.x + a2.y + 1.0f);   // forget bias
        const float go = fast_sig (a3.x + a3.y);
        c1 = fmaf(gf, c1, gi * gj);
        h1own = go * fast_tanh(c1);
        h_lds[l] = h1own;            // publish for t+1 (same-wave, in-order)

        // ---- layer-2 head: products + in-row DPP reduce (consumed at t+1) --
        r0 = row_reduce16(h1own * w2r[0]);
        r1 = row_reduce16(h1own * w2r[1]);
        r2 = row_reduce16(h1own * w2r[2]);
        r3 = row_reduce16(h1own * w2r[3]);
    }

    // ---- final layer-2 tail (t == kT) ----
    {
        const float zi = rl(r0,0)+rl(r0,16)+rl(r0,32)+rl(r0,48) + b2v.x + h2 * w2t.x;
        const float zj = rl(r1,0)+rl(r1,16)+rl(r1,32)+rl(r1,48) + b2v.y + h2 * w2t.y;
        const float zf = rl(r2,0)+rl(r2,16)+rl(r2,32)+rl(r2,48) + b2v.z + h2 * w2t.z;
        const float zo = rl(r3,0)+rl(r3,16)+rl(r3,32)+rl(r3,48) + b2v.w + h2 * w2t.w;
        c2 = fast_sig(zf + 1.0f) * c2 + fast_sig(zi) * fast_tanh(zj);
        h2 = fast_sig(zo) * fast_tanh(c2);
        if (l == 0) out_lds[kT - 1] = h2;
    }

    // ---- bulk coalesced store of the whole output row ----
    for (int i = l; i < kT / 4; i += 64) outg4[i] = out4_lds[i];
}

extern "C" void kernel_launch(void* const* d_in, const int* in_sizes, int n_in,
                              void* d_out, int out_size, void* d_ws, size_t ws_size,
                              hipStream_t stream) {
    const float* x  = (const float*)d_in[0];
    const float* W1 = (const float*)d_in[1];
    const float* b1 = (const float*)d_in[2];
    const float* W2 = (const float*)d_in[3];
    const float* b2 = (const float*)d_in[4];
    float* out = (float*)d_out;
    lstm2_kernel<<<kB, 64, 0, stream>>>(x, W1, b1, W2, b2, out);
}

// Round 4
// 1228.417 us; speedup vs baseline: 1.4523x; 1.4523x over previous
//
#include <hip/hip_runtime.h>

// 2-layer stacked LSTM: B=256, T=2048, H=64, layer2 hidden=1.
//
// Round-7: design to the OBSERVED register grant instead of fighting the
// allocator. Evidence: R2/R3 granted ~184 VGPRs regardless of
// amdgpu_waves_per_eu(1)/(1,1); demand was ~360 -> permanent scratch spill
// (42ms cold dispatch, 15.7MB FETCH). Grant tracks LDS-implied occupancy
// (16.9KB -> ~2.8 waves/EU -> 512/2.8 = 184).
//
// Structure: 2 waves per batch element (256 blocks x 128 threads).
//  - Lane = (unit u = w*32 + (l&31), h-half p = l>>5). Each lane holds all
//    4 gates x 32 h-weights = 128 VGPRs as f32x2 (v_pk_fma_f32), reads only
//    its 32-element half of h (8 f32x4), halves combined with ONE
//    __shfl_xor(z, 32) per gate. Live ~190 VGPRs: FITS the grant.
//  - LDS padded to 60KB: LDS-implied occupancy = 1 wave/EU -> VGPR budget
//    formula gives ~512. Free: grid is 1 block/CU anyway (256 blocks).
//  - ONE __syncthreads per step; h_lds and the layer-2 stage double-buffered.
//  - Layer 2 split for balance: wave1 = head (h1(t-1) . W2 dot, staged to
//    LDS), wave0 = tail (serial c2/h2 recurrence, deferred one step) --
//    same deferral math as the proven R2 scheme.
constexpr int kT = 2048;
constexpr int kB = 256;
constexpr int kH = 64;

typedef __attribute__((ext_vector_type(2))) float f32x2;
typedef __attribute__((ext_vector_type(4))) float f32x4;

__device__ __forceinline__ float fast_sig(float x) {
    return __builtin_amdgcn_rcpf(1.0f + __expf(-x));
}
__device__ __forceinline__ float fast_tanh(float x) {
    float t = __expf(2.0f * x);
    return 1.0f - 2.0f * __builtin_amdgcn_rcpf(t + 1.0f);
}

__global__ __launch_bounds__(128)
__attribute__((amdgpu_waves_per_eu(1, 1)))
void lstm2_kernel(
    const float* __restrict__ x, const float* __restrict__ W1,
    const float* __restrict__ b1, const float* __restrict__ W2,
    const float* __restrict__ b2, float* __restrict__ out)
{
    __shared__ f32x4 x4_lds[kT / 4];      // 8 KB: whole input row
    __shared__ f32x4 out4_lds[kT / 4];    // 8 KB: h2 staging
    __shared__ float h_lds[2][kH];        // 512 B: double-buffered h1
    __shared__ f32x4 z4_lds[2];           // 32 B: double-buffered layer-2 stage
    __shared__ float pad_lds[11128];      // pad total LDS to 60 KB (see above)

    float* x_lds = (float*)x4_lds;
    float* out_lds = (float*)out4_lds;

    const int tid = threadIdx.x;
    const int b = blockIdx.x;
    const int w = tid >> 6;       // wave 0 / 1
    const int l = tid & 63;       // lane
    const int p = l >> 5;         // h-half: 0 -> h[0:32), 1 -> h[32:64)
    const int u = w * 32 + (l & 31);  // layer-1 unit owned by this lane

    const f32x4* xg4 = (const f32x4*)(x + (size_t)b * kT);
    f32x4* outg4 = (f32x4*)(out + (size_t)b * kT);

    for (int i = tid; i < kT / 4; i += 128) x4_lds[i] = xg4[i];
    if (tid < kH) { h_lds[0][tid] = 0.0f; h_lds[1][tid] = 0.0f; }
    // keep the pad alive (condition is never true at runtime, opaque to LLVM)
    if (b == 0x7fffffff) pad_lds[tid] = x[0];

    // ---- layer-1 weights: 4 gates x 32 h-entries for unit u, half p ----
    // wp[g][j].x pairs with h[base+2j], .y with h[base+2j+1]; W1 row r+1
    // multiplies h[r]. Gate-major columns: i, j, f, o quarters.
    f32x2 wp[4][16];
    float w0g[4], bg[4];
    const int base = p * 32;
    #pragma unroll
    for (int g = 0; g < 4; ++g) {
        const int col = g * 64 + u;
        w0g[g] = W1[col];
        bg[g]  = b1[col];
        #pragma unroll
        for (int j = 0; j < 16; ++j) {
            wp[g][j].x = W1[(base + 2 * j + 1) * 256 + col];
            wp[g][j].y = W1[(base + 2 * j + 2) * 256 + col];
        }
    }
    // ---- layer-2 head weights (loaded on BOTH waves; wave0 needs them
    // only for the epilogue) ----
    const int s = l & 15, gg = l >> 4;
    float w2p0 = W2[(s +  0) * 4 + gg];
    float w2p1 = W2[(s + 16) * 4 + gg];
    float w2p2 = W2[(s + 32) * 4 + gg];
    float w2p3 = W2[(s + 48) * 4 + gg];
    float b2g  = b2[gg];
    f32x4 w2t = ((const f32x4*)W2)[kH];   // W2[64][0..3]: h2 recurrent row

    // ---- PIN loop invariants (opaque RMW blocks rematerialization) ----
    #pragma unroll
    for (int g = 0; g < 4; ++g) {
        #pragma unroll
        for (int j = 0; j < 16; ++j) asm volatile("" : "+v"(wp[g][j]));
        asm volatile("" : "+v"(w0g[g]), "+v"(bg[g]));
    }
    asm volatile("" : "+v"(w2p0), "+v"(w2p1), "+v"(w2p2), "+v"(w2p3));
    asm volatile("" : "+v"(w2t), "+v"(b2g));

    float c1 = 0.0f, c2 = 0.0f, h2 = 0.0f;

    __syncthreads();

    #pragma unroll 1
    for (int t = 0; t < kT; ++t) {
        const int cur = t & 1, nxt = cur ^ 1;

        const float xt = x_lds[t];
        f32x4 hp[8];
        const f32x4* hb4 = (const f32x4*)h_lds[cur];
        #pragma unroll
        for (int k = 0; k < 8; ++k) hp[k] = hb4[p * 8 + k];

        if (w == 0) {
            // ---- layer-2 tail: c2/h2 recurrence for output step t-2 ----
            if (t >= 2) {
                const f32x4 z4 = z4_lds[nxt];     // staged at t-1 (bias incl.)
                const float zi = z4.x + h2 * w2t.x;
                const float zj = z4.y + h2 * w2t.y;
                const float zf = z4.z + h2 * w2t.z;
                const float zo = z4.w + h2 * w2t.w;
                c2 = fast_sig(zf + 1.0f) * c2 + fast_sig(zi) * fast_tanh(zj);
                h2 = fast_sig(zo) * fast_tanh(c2);
                if (l == 0) out_lds[t - 2] = h2;
            }
        } else {
            // ---- layer-2 head: xdot(t-1) = h1(t-1) . W2 cols, staged ----
            const float* hb = h_lds[cur];
            float pr = hb[s] * w2p0;
            pr = fmaf(hb[s + 16], w2p1, pr);
            pr = fmaf(hb[s + 32], w2p2, pr);
            pr = fmaf(hb[s + 48], w2p3, pr);
            pr += __shfl_xor(pr, 1);
            pr += __shfl_xor(pr, 2);
            pr += __shfl_xor(pr, 4);
            pr += __shfl_xor(pr, 8);
            if ((l & 15) == 0) ((float*)&z4_lds[cur])[gg] = pr + b2g;
        }

        // ---- layer-1: z[g] = b + x*w0 + sum over this lane's h-half ----
        f32x2 a0, a1, a2, a3;
        a0.x = (p == 0) ? fmaf(xt, w0g[0], bg[0]) : 0.0f; a0.y = 0.0f;
        a1.x = (p == 0) ? fmaf(xt, w0g[1], bg[1]) : 0.0f; a1.y = 0.0f;
        a2.x = (p == 0) ? fmaf(xt, w0g[2], bg[2]) : 0.0f; a2.y = 0.0f;
        a3.x = (p == 0) ? fmaf(xt, w0g[3], bg[3]) : 0.0f; a3.y = 0.0f;
        #pragma unroll
        for (int k = 0; k < 8; ++k) {
            const f32x2 lo = hp[k].xy;
            const f32x2 hi = hp[k].zw;
            a0 += lo * wp[0][2*k]; a0 += hi * wp[0][2*k+1];
            a1 += lo * wp[1][2*k]; a1 += hi * wp[1][2*k+1];
            a2 += lo * wp[2][2*k]; a2 += hi * wp[2][2*k+1];
            a3 += lo * wp[3][2*k]; a3 += hi * wp[3][2*k+1];
        }
        float zi = a0.x + a0.y; zi += __shfl_xor(zi, 32);
        float zj = a1.x + a1.y; zj += __shfl_xor(zj, 32);
        float zf = a2.x + a2.y; zf += __shfl_xor(zf, 32);
        float zo = a3.x + a3.y; zo += __shfl_xor(zo, 32);
        const float gi = fast_sig(zi);
        const float gj = fast_tanh(zj);
        const float gf = fast_sig(zf + 1.0f);     // forget bias
        const float go = fast_sig(zo);
        c1 = fmaf(gf, c1, gi * gj);               // redundant in both halves
        const float h1n = go * fast_tanh(c1);
        if (p == 0) h_lds[nxt][u] = h1n;          // each wave writes its 32

        __syncthreads();
    }

    // ---- epilogue (wave 0): outputs T-2 and T-1 ----
    if (w == 0) {
        {   // out[T-2]: staged by wave1 at t = T-1 into z4_lds[(T-1)&1] = [1]
            const f32x4 z4 = z4_lds[1];
            const float zi = z4.x + h2 * w2t.x;
            const float zj = z4.y + h2 * w2t.y;
            const float zf = z4.z + h2 * w2t.z;
            const float zo = z4.w + h2 * w2t.w;
            c2 = fast_sig(zf + 1.0f) * c2 + fast_sig(zi) * fast_tanh(zj);
            h2 = fast_sig(zo) * fast_tanh(c2);
            if (l == 0) out_lds[kT - 2] = h2;
        }
        {   // out[T-1]: head computed here from h1(T-1) = h_lds[kT&1] = [0]
            const float* hb = h_lds[0];
            float pr = hb[s] * w2p0;
            pr = fmaf(hb[s + 16], w2p1, pr);
            pr = fmaf(hb[s + 32], w2p2, pr);
            pr = fmaf(hb[s + 48], w2p3, pr);
            pr += __shfl_xor(pr, 1);
            pr += __shfl_xor(pr, 2);
            pr += __shfl_xor(pr, 4);
            pr += __shfl_xor(pr, 8);
            const float prb = pr + b2g;
            const float zi = __shfl(prb,  0) + h2 * w2t.x;
            const float zj = __shfl(prb, 16) + h2 * w2t.y;
            const float zf = __shfl(prb, 32) + h2 * w2t.z;
            const float zo = __shfl(prb, 48) + h2 * w2t.w;
            c2 = fast_sig(zf + 1.0f) * c2 + fast_sig(zi) * fast_tanh(zj);
            h2 = fast_sig(zo) * fast_tanh(c2);
            if (l == 0) out_lds[kT - 1] = h2;
        }
    }

    // ---- bulk coalesced store of the whole output row ----
    __syncthreads();
    for (int i = tid; i < kT / 4; i += 128) outg4[i] = out4_lds[i];
}

extern "C" void kernel_launch(void* const* d_in, const int* in_sizes, int n_in,
                              void* d_out, int out_size, void* d_ws, size_t ws_size,
                              hipStream_t stream) {
    const float* x  = (const float*)d_in[0];
    const float* W1 = (const float*)d_in[1];
    const float* b1 = (const float*)d_in[2];
    const float* W2 = (const float*)d_in[3];
    const float* b2 = (const float*)d_in[4];
    float* out = (float*)d_out;
    lstm2_kernel<<<kB, 128, 0, stream>>>(x, W1, b1, W2, b2, out);
}